// Round 3
// baseline (288.395 us; speedup 1.0000x reference)
//
#include <hip/hip_runtime.h>
#include <math.h>

// Label-smoothed cross-entropy loss (XentLoss), MI355X.
// Inputs:
//   d_in[0]: log_probs  float32, (B*T, V) flat = 4096 x 32000
//   d_in[1]: trg        int32,   (B*T,)
// Output: d_out[0] = scalar float32 sum over rows.
//
// Memory-bound: 524 MB read -> roofline ~83 us @ 6.3 TB/s achievable.
// Single fused kernel: per-row block reduction + last-block-done final sum
// (fixed-order summation -> bitwise deterministic across replays).

#define SMOOTHING 0.1

// Native Clang vector type: __builtin_nontemporal_load requires a real
// vector type, not HIP's float4 class.
typedef float f32x4 __attribute__((ext_vector_type(4)));

__global__ __launch_bounds__(256) void xent_fused_kernel(
    const float* __restrict__ lp, const int* __restrict__ trg,
    float* __restrict__ row_out, unsigned int* __restrict__ counter,
    float* __restrict__ out, int V, int rows) {
  const int row = blockIdx.x;
  const float* rp = lp + (size_t)row * (size_t)V;
  const int tid = threadIdx.x;

  // ---- row sum: 4-way unrolled nontemporal 16B loads ----
  const int nvec = V >> 2;  // 8000 for V=32000
  const f32x4* rp4 = reinterpret_cast<const f32x4*>(rp);
  float s0 = 0.0f, s1 = 0.0f, s2 = 0.0f, s3 = 0.0f;
  int i = tid;
  for (; i + 768 < nvec; i += 1024) {
    f32x4 a = __builtin_nontemporal_load(&rp4[i]);
    f32x4 b = __builtin_nontemporal_load(&rp4[i + 256]);
    f32x4 c = __builtin_nontemporal_load(&rp4[i + 512]);
    f32x4 d = __builtin_nontemporal_load(&rp4[i + 768]);
    s0 += (a.x + a.y) + (a.z + a.w);
    s1 += (b.x + b.y) + (b.z + b.w);
    s2 += (c.x + c.y) + (c.z + c.w);
    s3 += (d.x + d.y) + (d.z + d.w);
  }
  for (; i < nvec; i += 256) {
    f32x4 v = __builtin_nontemporal_load(&rp4[i]);
    s0 += (v.x + v.y) + (v.z + v.w);
  }
  // scalar tail (V % 4 != 0 case; no-op for 32000)
  for (int j = (nvec << 2) + tid; j < V; j += 256) s0 += rp[j];
  float s = (s0 + s1) + (s2 + s3);

  // ---- wave (64-lane) shuffle reduce + cross-wave LDS reduce ----
  #pragma unroll
  for (int off = 32; off > 0; off >>= 1) s += __shfl_down(s, off, 64);

  __shared__ float wsum[4];
  __shared__ bool amLast;
  const int lane = tid & 63;
  const int wave = tid >> 6;
  if (lane == 0) wsum[wave] = s;
  __syncthreads();

  if (tid == 0) {
    float lp_sum = wsum[0] + wsum[1] + wsum[2] + wsum[3];
    const int t = trg[row];
    const float lp_t = rp[t];
    const float lp_pad = rp[0];

    const double conf = 1.0 - SMOOTHING;
    const double sm = SMOOTHING / (double)(V - 2);
    const double log_conf = log(conf);
    const double log_sm = log(sm);

    double rv = conf * (log_conf - (double)lp_t)
              + sm * (double)(V - 2) * log_sm
              - sm * ((double)lp_sum - (double)lp_t - (double)lp_pad);
    float rvf = (t != 0) ? (float)rv : 0.0f;

    // device-scope publish of this row's partial
    __hip_atomic_store(&row_out[row], rvf, __ATOMIC_RELAXED,
                       __HIP_MEMORY_SCOPE_AGENT);
    __threadfence();  // release: partial visible before counter bump
    unsigned prev = atomicAdd(counter, 1u);
    amLast = (prev == (unsigned)(rows - 1));
  }
  __syncthreads();

  // ---- last block: deterministic fixed-order final sum ----
  if (amLast) {
    __threadfence();  // acquire
    float t = 0.0f;
    for (int j = tid; j < rows; j += 256) {
      t += __hip_atomic_load(&row_out[j], __ATOMIC_RELAXED,
                             __HIP_MEMORY_SCOPE_AGENT);
    }
    #pragma unroll
    for (int off = 32; off > 0; off >>= 1) t += __shfl_down(t, off, 64);
    __shared__ float fsum[4];
    if (lane == 0) fsum[wave] = t;
    __syncthreads();
    if (tid == 0) out[0] = fsum[0] + fsum[1] + fsum[2] + fsum[3];
  }
}

extern "C" void kernel_launch(void* const* d_in, const int* in_sizes, int n_in,
                              void* d_out, int out_size, void* d_ws, size_t ws_size,
                              hipStream_t stream) {
  const float* lp = (const float*)d_in[0];
  const int* trg = (const int*)d_in[1];
  float* out = (float*)d_out;

  const int rows = in_sizes[1];            // B*T = 4096
  const int V = in_sizes[0] / rows;        // 32000

  float* row_out = (float*)d_ws;                               // rows floats
  unsigned int* counter =
      (unsigned int*)((char*)d_ws + (((size_t)rows * 4 + 255) & ~(size_t)255));

  (void)hipMemsetAsync(counter, 0, sizeof(unsigned int), stream);
  xent_fused_kernel<<<rows, 256, 0, stream>>>(lp, trg, row_out, counter, out,
                                              V, rows);
}

// Round 4
// 97.786 us; speedup vs baseline: 2.9493x; 2.9493x over previous
//
#include <hip/hip_runtime.h>
#include <math.h>

// Label-smoothed cross-entropy loss (XentLoss), MI355X.
// Inputs:
//   d_in[0]: log_probs  float32, (B*T, V) flat = 4096 x 32000
//   d_in[1]: trg        int32,   (B*T,)
// Output: d_out[0] = scalar float32 sum over rows.
//
// Memory-bound: 524 MB read -> roofline ~83 us @ 6.3 TB/s achievable.
// Two kernels (R1 structure): per-row partials, then one-block final sum.
// R3 post-mortem: fused last-block-done with agent-scope __threadfence()
// cost ~190us (per-XCD L2 writeback/inv on every block on 8-XCD part).
// Keep it simple: no fences, no atomics, bitwise-deterministic.

#define SMOOTHING 0.1

// Native Clang vector type for clean dwordx4 codegen.
typedef float f32x4 __attribute__((ext_vector_type(4)));

__global__ __launch_bounds__(256) void xent_row_kernel(
    const float* __restrict__ lp, const int* __restrict__ trg,
    float* __restrict__ row_out, int V) {
  const int row = blockIdx.x;
  const float* rp = lp + (size_t)row * (size_t)V;
  const int tid = threadIdx.x;

  // ---- row sum: 4-way unrolled 16B loads, independent accumulators ----
  const int nvec = V >> 2;  // 8000 for V=32000
  const f32x4* rp4 = reinterpret_cast<const f32x4*>(rp);
  float s0 = 0.0f, s1 = 0.0f, s2 = 0.0f, s3 = 0.0f;
  int i = tid;
  for (; i + 768 < nvec; i += 1024) {
    f32x4 a = rp4[i];
    f32x4 b = rp4[i + 256];
    f32x4 c = rp4[i + 512];
    f32x4 d = rp4[i + 768];
    s0 += (a.x + a.y) + (a.z + a.w);
    s1 += (b.x + b.y) + (b.z + b.w);
    s2 += (c.x + c.y) + (c.z + c.w);
    s3 += (d.x + d.y) + (d.z + d.w);
  }
  for (; i < nvec; i += 256) {
    f32x4 v = rp4[i];
    s0 += (v.x + v.y) + (v.z + v.w);
  }
  // scalar tail (V % 4 != 0 case; no-op for 32000)
  for (int j = (nvec << 2) + tid; j < V; j += 256) s0 += rp[j];
  float s = (s0 + s1) + (s2 + s3);

  // ---- wave (64-lane) shuffle reduce + cross-wave LDS reduce ----
  #pragma unroll
  for (int off = 32; off > 0; off >>= 1) s += __shfl_down(s, off, 64);

  __shared__ float wsum[4];
  const int lane = tid & 63;
  const int wave = tid >> 6;
  if (lane == 0) wsum[wave] = s;
  __syncthreads();

  if (tid == 0) {
    float lp_sum = wsum[0] + wsum[1] + wsum[2] + wsum[3];
    const int t = trg[row];
    const float lp_t = rp[t];
    const float lp_pad = rp[0];

    // Constants in double, matching the reference's Python-double folding.
    const double conf = 1.0 - SMOOTHING;
    const double sm = SMOOTHING / (double)(V - 2);
    const double log_conf = log(conf);
    const double log_sm = log(sm);

    double rv = conf * (log_conf - (double)lp_t)
              + sm * (double)(V - 2) * log_sm
              - sm * ((double)lp_sum - (double)lp_t - (double)lp_pad);
    row_out[row] = (t != 0) ? (float)rv : 0.0f;
  }
}

// Deterministic single-block final sum of the per-row partials.
__global__ __launch_bounds__(256) void xent_final_sum(
    const float* __restrict__ rows, float* __restrict__ out, int n) {
  const int tid = threadIdx.x;
  float s = 0.0f;
  for (int i = tid; i < n; i += 256) s += rows[i];

  #pragma unroll
  for (int off = 32; off > 0; off >>= 1) s += __shfl_down(s, off, 64);

  __shared__ float wsum[4];
  const int lane = tid & 63;
  const int wave = tid >> 6;
  if (lane == 0) wsum[wave] = s;
  __syncthreads();

  if (tid == 0) out[0] = wsum[0] + wsum[1] + wsum[2] + wsum[3];
}

extern "C" void kernel_launch(void* const* d_in, const int* in_sizes, int n_in,
                              void* d_out, int out_size, void* d_ws, size_t ws_size,
                              hipStream_t stream) {
  const float* lp = (const float*)d_in[0];
  const int* trg = (const int*)d_in[1];
  float* out = (float*)d_out;

  const int rows = in_sizes[1];            // B*T = 4096
  const int V = in_sizes[0] / rows;        // 32000

  float* row_out = (float*)d_ws;           // rows * 4 bytes scratch

  xent_row_kernel<<<rows, 256, 0, stream>>>(lp, trg, row_out, V);
  xent_final_sum<<<1, 256, 0, stream>>>(row_out, out, rows);
}

// Round 5
// 82.758 us; speedup vs baseline: 3.4848x; 1.1816x over previous
//
#include <hip/hip_runtime.h>
#include <math.h>

// Label-smoothed cross-entropy loss (XentLoss), MI355X.
// Inputs:
//   d_in[0]: log_probs  float32, (B*T, V) flat = 4096 x 32000
//   d_in[1]: trg        int32,   (B*T,)
// Output: d_out[0] = scalar float32 sum over rows.
//
// Memory-bound: 524 MB read -> roofline ~83 us @ 6.3 TB/s achievable.
// Two kernels: per-row partials, then one-block final sum (deterministic).
// R3 post-mortem: agent-scope fence fusion cost ~190us on 8-XCD part.
// R5: prefetch epilogue loads before row loop; nontemporal streaming loads
//     (isolated from fences this time); vectorized final_sum.

#define SMOOTHING 0.1

// Native Clang vector type (required by __builtin_nontemporal_load).
typedef float f32x4 __attribute__((ext_vector_type(4)));

__global__ __launch_bounds__(256) void xent_row_kernel(
    const float* __restrict__ lp, const int* __restrict__ trg,
    float* __restrict__ row_out, int V) {
  const int row = blockIdx.x;
  const float* rp = lp + (size_t)row * (size_t)V;
  const int tid = threadIdx.x;

  // ---- epilogue prefetch: issue the dependent-load chain EARLY so its
  // latency hides under the streaming row loop (used only by thread 0).
  int t = 0;
  float lp_t = 0.0f, lp_pad = 0.0f;
  if (tid == 0) {
    t = trg[row];
    lp_t = rp[t];
    lp_pad = rp[0];
  }

  // ---- row sum: 4-way unrolled nontemporal 16B loads ----
  const int nvec = V >> 2;  // 8000 for V=32000
  const f32x4* rp4 = reinterpret_cast<const f32x4*>(rp);
  float s0 = 0.0f, s1 = 0.0f, s2 = 0.0f, s3 = 0.0f;
  int i = tid;
  for (; i + 768 < nvec; i += 1024) {
    f32x4 a = __builtin_nontemporal_load(&rp4[i]);
    f32x4 b = __builtin_nontemporal_load(&rp4[i + 256]);
    f32x4 c = __builtin_nontemporal_load(&rp4[i + 512]);
    f32x4 d = __builtin_nontemporal_load(&rp4[i + 768]);
    s0 += (a.x + a.y) + (a.z + a.w);
    s1 += (b.x + b.y) + (b.z + b.w);
    s2 += (c.x + c.y) + (c.z + c.w);
    s3 += (d.x + d.y) + (d.z + d.w);
  }
  for (; i < nvec; i += 256) {
    f32x4 v = __builtin_nontemporal_load(&rp4[i]);
    s0 += (v.x + v.y) + (v.z + v.w);
  }
  // scalar tail (V % 4 != 0 case; no-op for 32000)
  for (int j = (nvec << 2) + tid; j < V; j += 256) s0 += rp[j];
  float s = (s0 + s1) + (s2 + s3);

  // ---- wave (64-lane) shuffle reduce + cross-wave LDS reduce ----
  #pragma unroll
  for (int off = 32; off > 0; off >>= 1) s += __shfl_down(s, off, 64);

  __shared__ float wsum[4];
  const int lane = tid & 63;
  const int wave = tid >> 6;
  if (lane == 0) wsum[wave] = s;
  __syncthreads();

  if (tid == 0) {
    float lp_sum = wsum[0] + wsum[1] + wsum[2] + wsum[3];

    // Constants in double, matching the reference's Python-double folding.
    const double conf = 1.0 - SMOOTHING;
    const double sm = SMOOTHING / (double)(V - 2);
    const double log_conf = log(conf);
    const double log_sm = log(sm);

    double rv = conf * (log_conf - (double)lp_t)
              + sm * (double)(V - 2) * log_sm
              - sm * ((double)lp_sum - (double)lp_t - (double)lp_pad);
    row_out[row] = (t != 0) ? (float)rv : 0.0f;
  }
}

// Deterministic single-block final sum of the per-row partials (vectorized).
__global__ __launch_bounds__(256) void xent_final_sum(
    const float* __restrict__ rows, float* __restrict__ out, int n) {
  const int tid = threadIdx.x;
  float s = 0.0f;
  const int nv = n >> 2;
  const f32x4* r4 = reinterpret_cast<const f32x4*>(rows);
  for (int i = tid; i < nv; i += 256) {
    f32x4 v = r4[i];
    s += (v.x + v.y) + (v.z + v.w);
  }
  for (int i = (nv << 2) + tid; i < n; i += 256) s += rows[i];

  #pragma unroll
  for (int off = 32; off > 0; off >>= 1) s += __shfl_down(s, off, 64);

  __shared__ float wsum[4];
  const int lane = tid & 63;
  const int wave = tid >> 6;
  if (lane == 0) wsum[wave] = s;
  __syncthreads();

  if (tid == 0) out[0] = wsum[0] + wsum[1] + wsum[2] + wsum[3];
}

extern "C" void kernel_launch(void* const* d_in, const int* in_sizes, int n_in,
                              void* d_out, int out_size, void* d_ws, size_t ws_size,
                              hipStream_t stream) {
  const float* lp = (const float*)d_in[0];
  const int* trg = (const int*)d_in[1];
  float* out = (float*)d_out;

  const int rows = in_sizes[1];            // B*T = 4096
  const int V = in_sizes[0] / rows;        // 32000

  float* row_out = (float*)d_ws;           // rows * 4 bytes scratch

  xent_row_kernel<<<rows, 256, 0, stream>>>(lp, trg, row_out, V);
  xent_final_sum<<<1, 256, 0, stream>>>(row_out, out, rows);
}